// Round 1
// baseline (2358.001 us; speedup 1.0000x reference)
//
#include <hip/hip_runtime.h>
#include <hip/hip_bf16.h>
#include <math.h>

#define B_ 16
#define C_ 32
#define N_ 500
#define T_ 64
#define L_ 4
#define BSTR (C_*N_*T_)              // 1024000
#define CSTR (N_*T_)                 // 32000
#define TENS ((size_t)B_*C_*N_*T_)   // 16384000
#define CNT_ 512000.0

typedef short s8v __attribute__((ext_vector_type(8)));
typedef float f4v __attribute__((ext_vector_type(4)));
typedef unsigned short u16;

// ---------------------------------------------------------------------------
__global__ __launch_bounds__(256) void zero_kernel(double* __restrict__ p) {
  p[threadIdx.x] = 0.0;   // 256 doubles = L_*64 stats slots
}

// ---------------------------------------------------------------------------
// Per-channel sum/sum-sq for BN, layer 0 only (reads x). fp64 exact.
__global__ __launch_bounds__(256) void stats_kernel(const float* __restrict__ h,
                                                    double* __restrict__ st) {
  int c = blockIdx.x, b = blockIdx.y, tid = threadIdx.x;
  const float4* p = (const float4*)(h + (size_t)b*BSTR + (size_t)c*CSTR);
  double s = 0.0, s2 = 0.0;
  for (int i = tid; i < CSTR/4; i += 256) {
    float4 v = p[i];
    s  += (double)v.x + (double)v.y + (double)v.z + (double)v.w;
    s2 += (double)v.x*v.x + (double)v.y*v.y + (double)v.z*v.z + (double)v.w*v.w;
  }
  __shared__ double sd[256], sd2[256];
  sd[tid] = s; sd2[tid] = s2; __syncthreads();
  for (int off = 128; off > 0; off >>= 1) {
    if (tid < off) { sd[tid] += sd[tid+off]; sd2[tid] += sd2[tid+off]; }
    __syncthreads();
  }
  if (tid == 0) { atomicAdd(&st[2*c], sd[0]); atomicAdd(&st[2*c+1], sd2[0]); }
}

// ---------------------------------------------------------------------------
// Build ATcat[w][k] bf16 hi/lo planes, w<512 (pad), k<1024 (two 512 supports).
__global__ __launch_bounds__(256) void aconv_kernel(const float* __restrict__ sup,
                                                    short* __restrict__ ATh,
                                                    short* __restrict__ ATl) {
  int idx = blockIdx.x*256 + threadIdx.x;   // 512*1024
  int k = idx & 1023, w = idx >> 10;
  int s = k >> 9, v = k & 511;
  float val = (v < N_ && w < N_) ? sup[((size_t)s*N_ + v)*N_ + w] : 0.f;
  __hip_bfloat16 bh = __float2bfloat16(val);
  float fh = __bfloat162float(bh);
  __hip_bfloat16 bl = __float2bfloat16(val - fh);
  ATh[idx] = *(short*)&bh;
  ATl[idx] = *(short*)&bl;
}

// ---------------------------------------------------------------------------
// One-time W1 transpose: W1T[c][k] = W1[k][c], 2048 elems.
__global__ __launch_bounds__(256) void w1t_kernel(const float* __restrict__ W1,
                                                  float* __restrict__ W1T) {
  int idx = blockIdx.x*256 + threadIdx.x;   // 2048
  int c = idx >> 6, k = idx & 63;
  W1T[c*64 + k] = W1[k*32 + c];
}

// ---------------------------------------------------------------------------
// Fused BN -> ReLU -> {res 1x1, causal convs K=3} -> tanh*sigmoid -> z (LDS)
// -> three 32x32 pointwise mixes. TWO nodes per block.
// Y1/Y2 now emitted as bf16 ushort planes (diffusion B operand is single-plane
// bf16 there; lo-plane contribution ~1e-5 << tolerance). Y0 may alias input h.
__global__ __launch_bounds__(512) void fuse3_kernel(
    const float* __restrict__ h, const double* __restrict__ st,
    const float* __restrict__ gamma, const float* __restrict__ beta,
    const float* __restrict__ rw, const float* __restrict__ rb,
    const float* __restrict__ aw, const float* __restrict__ ab,
    const float* __restrict__ gw, const float* __restrict__ gb,
    const float* __restrict__ gcw, const float* __restrict__ gcb,
    float* __restrict__ Y0, u16* __restrict__ Y1h, u16* __restrict__ Y2h)
{
  __shared__ float sh_h[2][C_*T_];   // raw h [nn][c][t]; later z [nn][o][t]
  __shared__ float sh_x[2][C_*68];   // relu(BN(h)) [nn][c][4 pad + 64]
  __shared__ float ssc[C_], ssb[C_];

  int tid = threadIdx.x;
  int bx  = blockIdx.x;
  int b = bx / 250, np = bx - b*250;
  size_t off0 = (size_t)b*BSTR + (size_t)(np*2)*T_;

  #pragma unroll
  for (int i = 0; i < 2; i++) {      // stage 2 nodes: 1024 float4
    int idx = tid + i*512;
    int nn = idx >> 9, r = idx & 511;
    int c = r >> 4, t4 = (r & 15) << 2;
    float4 v = *(const float4*)(h + off0 + (size_t)nn*T_ + (size_t)c*CSTR + t4);
    *(float4*)&sh_h[nn][c*T_ + t4] = v;
  }
  if (tid < C_) {
    double m = st[2*tid] * (1.0/CNT_);
    double v = st[2*tid+1] * (1.0/CNT_) - m*m;
    float sc = gamma[tid] * (float)(1.0 / sqrt(v + 1e-5));
    ssc[tid] = sc;
    ssb[tid] = beta[tid] - (float)m * sc;
  }
  if (tid < 256) { int nn = tid >> 7, c = (tid >> 2) & 31; sh_x[nn][c*68 + (tid & 3)] = 0.f; }
  __syncthreads();

  #pragma unroll
  for (int i = 0; i < 2; i++) {      // BN + ReLU into padded sh_x
    int idx = tid + i*512;
    int nn = idx >> 9, r = idx & 511;
    int c = r >> 4, t4 = (r & 15) << 2;
    float sc = ssc[c], sb = ssb[c];
    float4 v = *(const float4*)&sh_h[nn][c*T_ + t4];
    float4 rr;
    rr.x = fmaxf(fmaf(v.x, sc, sb), 0.f);
    rr.y = fmaxf(fmaf(v.y, sc, sb), 0.f);
    rr.z = fmaxf(fmaf(v.z, sc, sb), 0.f);
    rr.w = fmaxf(fmaf(v.w, sc, sb), 0.f);
    *(float4*)&sh_x[nn][c*68 + 4 + t4] = rr;
  }
  __syncthreads();

  int t = tid & 63;
  int og = __builtin_amdgcn_readfirstlane(tid >> 6);   // 0..7
  float racc[2][4] = {}, aacc[2][4] = {}, gacc[2][4] = {};
  for (int c = 0; c < C_; c++) {
    float wR[4], wA[4][3], wG[4][3];   // wave-uniform -> SGPRs
    #pragma unroll
    for (int jq = 0; jq < 4; jq++) {
      int oo = og*4 + jq;
      wR[jq] = rw[oo*C_ + c];
      const float* ap = aw + (oo*C_ + c)*3;
      const float* gp = gw + (oo*C_ + c)*3;
      wA[jq][0] = ap[0]; wA[jq][1] = ap[1]; wA[jq][2] = ap[2];
      wG[jq][0] = gp[0]; wG[jq][1] = gp[1]; wG[jq][2] = gp[2];
    }
    #pragma unroll
    for (int nn = 0; nn < 2; nn++) {
      float hvv = sh_h[nn][c*T_ + t];
      const float* xr = &sh_x[nn][c*68 + 2 + t];
      float xm2 = xr[0], xm1 = xr[1], x0c = xr[2];
      #pragma unroll
      for (int jq = 0; jq < 4; jq++) {
        racc[nn][jq] = fmaf(wR[jq], hvv, racc[nn][jq]);
        aacc[nn][jq] = fmaf(wA[jq][0], xm2, fmaf(wA[jq][1], xm1, fmaf(wA[jq][2], x0c, aacc[nn][jq])));
        gacc[nn][jq] = fmaf(wG[jq][0], xm2, fmaf(wG[jq][1], xm1, fmaf(wG[jq][2], x0c, gacc[nn][jq])));
      }
    }
  }
  float zv[2][4];
  #pragma unroll
  for (int nn = 0; nn < 2; nn++)
    #pragma unroll
    for (int jq = 0; jq < 4; jq++) {
      int oo = og*4 + jq;
      float a = aacc[nn][jq] + racc[nn][jq] + ab[oo] + rb[oo];
      float gg = gacc[nn][jq] + gb[oo];
      zv[nn][jq] = tanhf(a) * (1.f/(1.f + expf(-gg)));
    }
  __syncthreads();
  #pragma unroll
  for (int nn = 0; nn < 2; nn++)
    #pragma unroll
    for (int jq = 0; jq < 4; jq++) sh_h[nn][(og*4 + jq)*T_ + t] = zv[nn][jq];
  __syncthreads();

  float y0a[2][4] = {}, y1a[2][4] = {}, y2a[2][4] = {};
  for (int c = 0; c < C_; c++) {
    float g0[4], g1[4], g2[4];
    #pragma unroll
    for (int jq = 0; jq < 4; jq++) {
      const float* gr = gcw + (og*4 + jq)*96;
      g0[jq] = gr[c]; g1[jq] = gr[32 + c]; g2[jq] = gr[64 + c];
    }
    #pragma unroll
    for (int nn = 0; nn < 2; nn++) {
      float zc = sh_h[nn][c*T_ + t];
      #pragma unroll
      for (int jq = 0; jq < 4; jq++) {
        y0a[nn][jq] = fmaf(g0[jq], zc, y0a[nn][jq]);
        y1a[nn][jq] = fmaf(g1[jq], zc, y1a[nn][jq]);
        y2a[nn][jq] = fmaf(g2[jq], zc, y2a[nn][jq]);
      }
    }
  }
  #pragma unroll
  for (int nn = 0; nn < 2; nn++)
    #pragma unroll
    for (int jq = 0; jq < 4; jq++) {
      int oo = og*4 + jq;
      size_t pp = off0 + (size_t)nn*T_ + (size_t)oo*CSTR + t;
      Y0[pp] = y0a[nn][jq] + gcb[oo];
      __hip_bfloat16 b1 = __float2bfloat16(y1a[nn][jq]);
      __hip_bfloat16 b2 = __float2bfloat16(y2a[nn][jq]);
      Y1h[pp] = *(u16*)&b1;
      Y2h[pp] = *(u16*)&b2;
    }
}

// ---------------------------------------------------------------------------
// Diffusion: A split-bf16 (hi+lo) x B single-plane bf16 -> 2 MFMA per tile.
// T14 reg-prefetch pipeline: next k-tile's global loads are issued right
// after the staging barrier so their latency hides under LDS reads + MFMA.
// Fused next-layer BN stats in the epilogue.
__global__ __launch_bounds__(256) void diff3_kernel(
    const u16* __restrict__ Y1h, const u16* __restrict__ Y2h,
    const short* __restrict__ ATh, const short* __restrict__ ATl,
    float* __restrict__ out, double* __restrict__ stp)
{
  __shared__ short Asd[2][128*40];   // AT tile [plane][w_local][k(32)+pad8]
  __shared__ short Bsd[128*40];      // Y  tile [m_local][k(32)+pad8], bf16 hi only

  int tid = threadIdx.x;
  int bx = blockIdx.x;
  int mtile = bx & 15, wtile = bx >> 4;
  int b = blockIdx.y;
  int w0 = wtile << 7;

  int lane = tid & 63;
  int wave = __builtin_amdgcn_readfirstlane(tid >> 6);
  int wi = wave & 1, wj = wave >> 1;
  int l15 = lane & 15, quad = lane >> 4;

  int offA[4], offB[4];
  #pragma unroll
  for (int ti = 0; ti < 4; ti++) offA[ti] = (wi*64 + ti*16 + l15)*40 + quad*8;
  #pragma unroll
  for (int tj = 0; tj < 4; tj++) offB[tj] = (wj*64 + tj*16 + l15)*40 + quad*8;

  f4v acc[16];
  #pragma unroll
  for (int i = 0; i < 16; i++) acc[i] = (f4v){0.f, 0.f, 0.f, 0.f};

  int t_l = tid & 63;
  int g = tid >> 6;

  // prefetch registers (A: 4x int4 across 2 planes; B: 16 gathered ushorts)
  int4 rA[4];
  u16 rB[16];

  auto LOADA = [&](int k0) {
    #pragma unroll
    for (int i = 0; i < 4; i++) {
      int idx = tid + i*256;
      int kq = idx & 3, wl = (idx >> 2) & 127, pl = idx >> 9;
      rA[i] = *(const int4*)((pl ? ATl : ATh) + (size_t)(w0 + wl)*1024 + k0 + kq*8);
    }
  };
  auto LOADB = [&](int k0) {
    int s = k0 >> 9, v0 = k0 & 511;
    const u16* Ys = (s ? Y2h : Y1h) + (size_t)b*BSTR;
    #pragma unroll
    for (int i = 0; i < 2; i++) {
      int sel = g*2 + i;
      int oo = sel & 1, kq = sel >> 1;
      int o = mtile*2 + oo;
      #pragma unroll
      for (int j = 0; j < 8; j++) {
        int v = v0 + kq*8 + j;
        rB[i*8+j] = (v < N_) ? Ys[((size_t)o*N_ + v)*T_ + t_l] : (u16)0;
      }
    }
  };

  LOADA(0); LOADB(0);

  for (int k0 = 0; k0 < 1024; k0 += 32) {
    __syncthreads();                 // previous k-step done reading LDS
    #pragma unroll
    for (int i = 0; i < 4; i++) {    // stage A from regs
      int idx = tid + i*256;
      int kq = idx & 3, wl = (idx >> 2) & 127, pl = idx >> 9;
      *(int4*)&Asd[pl][wl*40 + kq*8] = rA[i];
    }
    #pragma unroll
    for (int i = 0; i < 2; i++) {    // stage B from regs
      int sel = g*2 + i;
      int oo = sel & 1, kq = sel >> 1;
      *(int4*)&Bsd[(oo*64 + t_l)*40 + kq*8] = *(const int4*)&rB[i*8];
    }
    __syncthreads();                 // staging visible

    if (k0 + 32 < 1024) {            // issue next tile's loads NOW (overlap)
      LOADA(k0 + 32);
      LOADB(k0 + 32);
    }

    s8v bh[4];
    #pragma unroll
    for (int tj = 0; tj < 4; tj++) bh[tj] = *(const s8v*)&Bsd[offB[tj]];
    #pragma unroll
    for (int ti = 0; ti < 4; ti++) {
      s8v ah = *(const s8v*)&Asd[0][offA[ti]];
      s8v al = *(const s8v*)&Asd[1][offA[ti]];
      #pragma unroll
      for (int tj = 0; tj < 4; tj++) {
        f4v d = acc[ti*4+tj];
        d = __builtin_amdgcn_mfma_f32_16x16x32_bf16(ah, bh[tj], d, 0, 0, 0);
        d = __builtin_amdgcn_mfma_f32_16x16x32_bf16(al, bh[tj], d, 0, 0, 0);
        acc[ti*4+tj] = d;
      }
    }
  }

  // epilogue: out += acc; capture final values for next layer's BN stats.
  // All of a thread's tiles belong to one o (o = mtile*2 + wj).
  int o = mtile*2 + wj;
  float s = 0.f, s2 = 0.f;
  #pragma unroll
  for (int tj = 0; tj < 4; tj++) {
    int t = tj*16 + l15;
    float* obase = out + (((size_t)b*C_ + o)*N_)*T_ + t;
    #pragma unroll
    for (int ti = 0; ti < 4; ti++) {
      int wbase = w0 + wi*64 + ti*16 + quad*4;
      #pragma unroll
      for (int r = 0; r < 4; r++) {
        int w = wbase + r;
        if (w < N_) {
          float* p = obase + (size_t)w*T_;
          float val = *p + acc[ti*4+tj][r];
          *p = val;
          s += val;
          s2 = fmaf(val, val, s2);
        }
      }
    }
  }
  if (stp) {
    #pragma unroll
    for (int d = 32; d > 0; d >>= 1) {
      s  += __shfl_down(s,  d, 64);
      s2 += __shfl_down(s2, d, 64);
    }
    if (lane == 0) {
      atomicAdd(&stp[2*o],     (double)s);
      atomicAdd(&stp[2*o + 1], (double)s2);
    }
  }
}

// ---------------------------------------------------------------------------
// Online-softmax attention, one node per wave, MLP fully in registers.
// Weight streams are contiguous s_load_dwordx16 batches; no LDS.
__global__ __launch_bounds__(256) void attn3_kernel(
    const float* __restrict__ hsrc, float* __restrict__ O,
    float* __restrict__ sden,
    const float* __restrict__ W1T, const float* __restrict__ b1,
    const float* __restrict__ W2, const float* __restrict__ b2,
    const float* __restrict__ w3, const float* __restrict__ b3,
    int init)
{
  int tid = threadIdx.x;
  int t = tid & 63;
  int g = __builtin_amdgcn_readfirstlane(tid >> 6);
  int bx = blockIdx.x;
  int b = bx / 125;
  int n = (bx - b*125)*4 + g;
  size_t off = (size_t)b*BSTR + (size_t)n*T_;

  float h1r[64];
  #pragma unroll
  for (int k = 0; k < 64; k++) h1r[k] = b1[k];
  for (int c = 0; c < C_; c++) {
    float xv = fmaxf(hsrc[off + (size_t)c*CSTR + t], 0.f);
    const float* wr = W1T + c*64;
    #pragma unroll
    for (int k = 0; k < 64; k++) h1r[k] = fmaf(wr[k], xv, h1r[k]);
  }
  #pragma unroll
  for (int k = 0; k < 64; k++) h1r[k] = fmaxf(h1r[k], 0.f);

  float e = b3[0];
  for (int j = 0; j < 64; j++) {
    const float* w2r = W2 + j*64;
    float a0 = 0.f, a1 = 0.f, a2 = 0.f, a3 = 0.f;
    #pragma unroll
    for (int i = 0; i < 64; i += 4) {
      a0 = fmaf(w2r[i+0], h1r[i+0], a0);
      a1 = fmaf(w2r[i+1], h1r[i+1], a1);
      a2 = fmaf(w2r[i+2], h1r[i+2], a2);
      a3 = fmaf(w2r[i+3], h1r[i+3], a3);
    }
    float a = b2[j] + ((a0+a1)+(a2+a3));
    e = fmaf(w3[j], fmaxf(a, 0.f), e);
  }
  float p = expf(e);      // e is O(1): no max-subtraction needed

  size_t si = (size_t)b*CSTR + (size_t)n*T_ + t;
  float so = init ? 0.f : sden[si];
  sden[si] = so + p;

  for (int c = 0; c < C_; c++) {
    size_t pi = off + (size_t)c*CSTR + t;
    float xv = fmaxf(hsrc[pi], 0.f);      // L1-hit re-read
    float ov = init ? 0.f : O[pi];
    O[pi] = fmaf(p, xv, ov);
  }
}

// ---------------------------------------------------------------------------
__global__ __launch_bounds__(256) void norm_kernel(float* __restrict__ O,
                                                   const float* __restrict__ sden) {
  unsigned idx = (blockIdx.x*256u + threadIdx.x) * 4u;
  unsigned b = idx / BSTR;
  unsigned r = idx - b*BSTR;
  unsigned nt = r % CSTR;
  float4 o = *(float4*)(O + idx);
  const float* sp = sden + (size_t)b*CSTR + nt;
  o.x /= sp[0]; o.y /= sp[1]; o.z /= sp[2]; o.w /= sp[3];
  *(float4*)(O + idx) = o;
}

// ---------------------------------------------------------------------------
extern "C" void kernel_launch(void* const* d_in, const int* in_sizes, int n_in,
                              void* d_out, int out_size, void* d_ws, size_t ws_size,
                              hipStream_t stream)
{
  const float* x    = (const float*)d_in[0];
  const float* sup  = (const float*)d_in[1];
  const float* bng  = (const float*)d_in[2];
  const float* bnb  = (const float*)d_in[3];
  const float* rw   = (const float*)d_in[4];
  const float* rb   = (const float*)d_in[5];
  const float* aw   = (const float*)d_in[6];
  const float* ab   = (const float*)d_in[7];
  const float* gw   = (const float*)d_in[8];
  const float* gb   = (const float*)d_in[9];
  const float* gcw  = (const float*)d_in[10];
  const float* gcb  = (const float*)d_in[11];
  const float* w1   = (const float*)d_in[12];
  const float* ab1  = (const float*)d_in[13];
  const float* w2   = (const float*)d_in[14];
  const float* ab2  = (const float*)d_in[15];
  const float* w3   = (const float*)d_in[16];
  const float* ab3  = (const float*)d_in[17];
  float* out = (float*)d_out;

  float* ws   = (float*)d_ws;
  float* bufA = ws;                       // Y0 / layer output h (float)
  u16*   Y1h  = (u16*)(ws + TENS);        // bf16 Y1 plane (fits old bufB)
  u16*   Y2h  = Y1h + TENS;               // bf16 Y2 plane
  float* sden = ws + (size_t)3*TENS;      // [B,N,T] softmax denom
  double* st  = (double*)(ws + (size_t)3*TENS + (size_t)B_*N_*T_);
  short* ATh  = (short*)(ws + (size_t)3*TENS + (size_t)B_*N_*T_ + 512);
  short* ATl  = ATh + (size_t)512*1024;
  float* W1T  = (float*)(ATl + (size_t)512*1024);

  zero_kernel<<<1, 256, 0, stream>>>(st);
  aconv_kernel<<<2048, 256, 0, stream>>>(sup, ATh, ATl);
  w1t_kernel<<<8, 256, 0, stream>>>(w1, W1T);
  stats_kernel<<<dim3(C_, B_), 256, 0, stream>>>(x, st);
  // slot 0 of the stack = x
  attn3_kernel<<<B_*125, 256, 0, stream>>>(x, out, sden, W1T, ab1, w2, ab2, w3, ab3, 1);

  const float* hcur = x;
  for (int l = 0; l < L_; l++) {
    fuse3_kernel<<<B_*250, 512, 0, stream>>>(
        hcur, st + l*64, bng + l*C_, bnb + l*C_,
        rw + l*C_*C_, rb + l*C_,
        aw + l*C_*C_*3, ab + l*C_,
        gw + l*C_*C_*3, gb + l*C_,
        gcw + l*C_*96, gcb + l*C_,
        bufA, Y1h, Y2h);
    diff3_kernel<<<dim3(64, B_), 256, 0, stream>>>(
        Y1h, Y2h, ATh, ATl, bufA, (l < L_-1) ? (st + (l+1)*64) : nullptr);
    attn3_kernel<<<B_*125, 256, 0, stream>>>(bufA, out, sden, W1T, ab1, w2, ab2, w3, ab3, 0);
    hcur = bufA;
  }
  norm_kernel<<<16000, 256, 0, stream>>>(out, sden);
}

// Round 2
// 2040.909 us; speedup vs baseline: 1.1554x; 1.1554x over previous
//
#include <hip/hip_runtime.h>
#include <hip/hip_bf16.h>
#include <math.h>

#define B_ 16
#define C_ 32
#define N_ 500
#define T_ 64
#define L_ 4
#define BSTR (C_*N_*T_)              // 1024000
#define CSTR (N_*T_)                 // 32000
#define TENS ((size_t)B_*C_*N_*T_)   // 16384000
#define CNT_ 512000.0

typedef short s8v __attribute__((ext_vector_type(8)));
typedef float f4v __attribute__((ext_vector_type(4)));
typedef unsigned short u16;

// ---------------------------------------------------------------------------
__global__ __launch_bounds__(256) void zero_kernel(double* __restrict__ p) {
  p[threadIdx.x] = 0.0;   // 256 doubles = L_*64 stats slots
}

// ---------------------------------------------------------------------------
// Per-channel sum/sum-sq for BN, layer 0 only (reads x). fp64 exact.
__global__ __launch_bounds__(256) void stats_kernel(const float* __restrict__ h,
                                                    double* __restrict__ st) {
  int c = blockIdx.x, b = blockIdx.y, tid = threadIdx.x;
  const float4* p = (const float4*)(h + (size_t)b*BSTR + (size_t)c*CSTR);
  double s = 0.0, s2 = 0.0;
  for (int i = tid; i < CSTR/4; i += 256) {
    float4 v = p[i];
    s  += (double)v.x + (double)v.y + (double)v.z + (double)v.w;
    s2 += (double)v.x*v.x + (double)v.y*v.y + (double)v.z*v.z + (double)v.w*v.w;
  }
  __shared__ double sd[256], sd2[256];
  sd[tid] = s; sd2[tid] = s2; __syncthreads();
  for (int off = 128; off > 0; off >>= 1) {
    if (tid < off) { sd[tid] += sd[tid+off]; sd2[tid] += sd2[tid+off]; }
    __syncthreads();
  }
  if (tid == 0) { atomicAdd(&st[2*c], sd[0]); atomicAdd(&st[2*c+1], sd2[0]); }
}

// ---------------------------------------------------------------------------
// Build ATcat[w][k] bf16 hi/lo planes, w<512 (pad), k<1024 (two 512 supports).
__global__ __launch_bounds__(256) void aconv_kernel(const float* __restrict__ sup,
                                                    short* __restrict__ ATh,
                                                    short* __restrict__ ATl) {
  int idx = blockIdx.x*256 + threadIdx.x;   // 512*1024
  int k = idx & 1023, w = idx >> 10;
  int s = k >> 9, v = k & 511;
  float val = (v < N_ && w < N_) ? sup[((size_t)s*N_ + v)*N_ + w] : 0.f;
  __hip_bfloat16 bh = __float2bfloat16(val);
  float fh = __bfloat162float(bh);
  __hip_bfloat16 bl = __float2bfloat16(val - fh);
  ATh[idx] = *(short*)&bh;
  ATl[idx] = *(short*)&bl;
}

// ---------------------------------------------------------------------------
// One-time W1 transpose: W1T[c][k] = W1[k][c], 2048 elems.
__global__ __launch_bounds__(256) void w1t_kernel(const float* __restrict__ W1,
                                                  float* __restrict__ W1T) {
  int idx = blockIdx.x*256 + threadIdx.x;   // 2048
  int c = idx >> 6, k = idx & 63;
  W1T[c*64 + k] = W1[k*32 + c];
}

// ---------------------------------------------------------------------------
// Fused BN -> ReLU -> {res 1x1, causal convs K=3} -> tanh*sigmoid -> z (LDS)
// -> three 32x32 pointwise mixes. TWO nodes per block.
// Y1/Y2 emitted as bf16 ushort planes (diffusion B operand is single-plane
// bf16; dropped lo-plane contribution ~1e-5 << tolerance). Y0 may alias h.
__global__ __launch_bounds__(512) void fuse3_kernel(
    const float* __restrict__ h, const double* __restrict__ st,
    const float* __restrict__ gamma, const float* __restrict__ beta,
    const float* __restrict__ rw, const float* __restrict__ rb,
    const float* __restrict__ aw, const float* __restrict__ ab,
    const float* __restrict__ gw, const float* __restrict__ gb,
    const float* __restrict__ gcw, const float* __restrict__ gcb,
    float* __restrict__ Y0, u16* __restrict__ Y1h, u16* __restrict__ Y2h)
{
  __shared__ float sh_h[2][C_*T_];   // raw h [nn][c][t]; later z [nn][o][t]
  __shared__ float sh_x[2][C_*68];   // relu(BN(h)) [nn][c][4 pad + 64]
  __shared__ float ssc[C_], ssb[C_];

  int tid = threadIdx.x;
  int bx  = blockIdx.x;
  int b = bx / 250, np = bx - b*250;
  size_t off0 = (size_t)b*BSTR + (size_t)(np*2)*T_;

  #pragma unroll
  for (int i = 0; i < 2; i++) {      // stage 2 nodes: 1024 float4
    int idx = tid + i*512;
    int nn = idx >> 9, r = idx & 511;
    int c = r >> 4, t4 = (r & 15) << 2;
    float4 v = *(const float4*)(h + off0 + (size_t)nn*T_ + (size_t)c*CSTR + t4);
    *(float4*)&sh_h[nn][c*T_ + t4] = v;
  }
  if (tid < C_) {
    double m = st[2*tid] * (1.0/CNT_);
    double v = st[2*tid+1] * (1.0/CNT_) - m*m;
    float sc = gamma[tid] * (float)(1.0 / sqrt(v + 1e-5));
    ssc[tid] = sc;
    ssb[tid] = beta[tid] - (float)m * sc;
  }
  if (tid < 256) { int nn = tid >> 7, c = (tid >> 2) & 31; sh_x[nn][c*68 + (tid & 3)] = 0.f; }
  __syncthreads();

  #pragma unroll
  for (int i = 0; i < 2; i++) {      // BN + ReLU into padded sh_x
    int idx = tid + i*512;
    int nn = idx >> 9, r = idx & 511;
    int c = r >> 4, t4 = (r & 15) << 2;
    float sc = ssc[c], sb = ssb[c];
    float4 v = *(const float4*)&sh_h[nn][c*T_ + t4];
    float4 rr;
    rr.x = fmaxf(fmaf(v.x, sc, sb), 0.f);
    rr.y = fmaxf(fmaf(v.y, sc, sb), 0.f);
    rr.z = fmaxf(fmaf(v.z, sc, sb), 0.f);
    rr.w = fmaxf(fmaf(v.w, sc, sb), 0.f);
    *(float4*)&sh_x[nn][c*68 + 4 + t4] = rr;
  }
  __syncthreads();

  int t = tid & 63;
  int og = __builtin_amdgcn_readfirstlane(tid >> 6);   // 0..7
  float racc[2][4] = {}, aacc[2][4] = {}, gacc[2][4] = {};
  for (int c = 0; c < C_; c++) {
    float wR[4], wA[4][3], wG[4][3];   // wave-uniform -> SGPRs
    #pragma unroll
    for (int jq = 0; jq < 4; jq++) {
      int oo = og*4 + jq;
      wR[jq] = rw[oo*C_ + c];
      const float* ap = aw + (oo*C_ + c)*3;
      const float* gp = gw + (oo*C_ + c)*3;
      wA[jq][0] = ap[0]; wA[jq][1] = ap[1]; wA[jq][2] = ap[2];
      wG[jq][0] = gp[0]; wG[jq][1] = gp[1]; wG[jq][2] = gp[2];
    }
    #pragma unroll
    for (int nn = 0; nn < 2; nn++) {
      float hvv = sh_h[nn][c*T_ + t];
      const float* xr = &sh_x[nn][c*68 + 2 + t];
      float xm2 = xr[0], xm1 = xr[1], x0c = xr[2];
      #pragma unroll
      for (int jq = 0; jq < 4; jq++) {
        racc[nn][jq] = fmaf(wR[jq], hvv, racc[nn][jq]);
        aacc[nn][jq] = fmaf(wA[jq][0], xm2, fmaf(wA[jq][1], xm1, fmaf(wA[jq][2], x0c, aacc[nn][jq])));
        gacc[nn][jq] = fmaf(wG[jq][0], xm2, fmaf(wG[jq][1], xm1, fmaf(wG[jq][2], x0c, gacc[nn][jq])));
      }
    }
  }
  float zv[2][4];
  #pragma unroll
  for (int nn = 0; nn < 2; nn++)
    #pragma unroll
    for (int jq = 0; jq < 4; jq++) {
      int oo = og*4 + jq;
      float a = aacc[nn][jq] + racc[nn][jq] + ab[oo] + rb[oo];
      float gg = gacc[nn][jq] + gb[oo];
      zv[nn][jq] = tanhf(a) * (1.f/(1.f + expf(-gg)));
    }
  __syncthreads();
  #pragma unroll
  for (int nn = 0; nn < 2; nn++)
    #pragma unroll
    for (int jq = 0; jq < 4; jq++) sh_h[nn][(og*4 + jq)*T_ + t] = zv[nn][jq];
  __syncthreads();

  float y0a[2][4] = {}, y1a[2][4] = {}, y2a[2][4] = {};
  for (int c = 0; c < C_; c++) {
    float g0[4], g1[4], g2[4];
    #pragma unroll
    for (int jq = 0; jq < 4; jq++) {
      const float* gr = gcw + (og*4 + jq)*96;
      g0[jq] = gr[c]; g1[jq] = gr[32 + c]; g2[jq] = gr[64 + c];
    }
    #pragma unroll
    for (int nn = 0; nn < 2; nn++) {
      float zc = sh_h[nn][c*T_ + t];
      #pragma unroll
      for (int jq = 0; jq < 4; jq++) {
        y0a[nn][jq] = fmaf(g0[jq], zc, y0a[nn][jq]);
        y1a[nn][jq] = fmaf(g1[jq], zc, y1a[nn][jq]);
        y2a[nn][jq] = fmaf(g2[jq], zc, y2a[nn][jq]);
      }
    }
  }
  #pragma unroll
  for (int nn = 0; nn < 2; nn++)
    #pragma unroll
    for (int jq = 0; jq < 4; jq++) {
      int oo = og*4 + jq;
      size_t pp = off0 + (size_t)nn*T_ + (size_t)oo*CSTR + t;
      Y0[pp] = y0a[nn][jq] + gcb[oo];
      __hip_bfloat16 b1 = __float2bfloat16(y1a[nn][jq]);
      __hip_bfloat16 b2 = __float2bfloat16(y2a[nn][jq]);
      Y1h[pp] = *(u16*)&b1;
      Y2h[pp] = *(u16*)&b2;
    }
}

// ---------------------------------------------------------------------------
// Diffusion: A split-bf16 (hi+lo) x B single-plane bf16 -> 2 MFMA per tile.
// Round-0 proven two-barrier schedule (in-phase loads; reg-prefetch pipeline
// regressed -19% in round 1 — barrier vmcnt(0) drain stalled lockstep waves).
// Fused next-layer BN stats in the epilogue.
__global__ __launch_bounds__(256) void diff3_kernel(
    const u16* __restrict__ Y1h, const u16* __restrict__ Y2h,
    const short* __restrict__ ATh, const short* __restrict__ ATl,
    float* __restrict__ out, double* __restrict__ stp)
{
  __shared__ short Asd[2][128*40];   // AT tile [plane][w_local][k(32)+pad8]
  __shared__ short Bsd[128*40];      // Y  tile [m_local][k(32)+pad8], bf16 hi only

  int tid = threadIdx.x;
  int bx = blockIdx.x;
  int mtile = bx & 15, wtile = bx >> 4;
  int b = blockIdx.y;
  int w0 = wtile << 7;

  int lane = tid & 63;
  int wave = __builtin_amdgcn_readfirstlane(tid >> 6);
  int wi = wave & 1, wj = wave >> 1;
  int l15 = lane & 15, quad = lane >> 4;

  int offA[4], offB[4];
  #pragma unroll
  for (int ti = 0; ti < 4; ti++) offA[ti] = (wi*64 + ti*16 + l15)*40 + quad*8;
  #pragma unroll
  for (int tj = 0; tj < 4; tj++) offB[tj] = (wj*64 + tj*16 + l15)*40 + quad*8;

  f4v acc[16];
  #pragma unroll
  for (int i = 0; i < 16; i++) acc[i] = (f4v){0.f, 0.f, 0.f, 0.f};

  int t_l = tid & 63;
  int g = tid >> 6;

  for (int k0 = 0; k0 < 1024; k0 += 32) {
    __syncthreads();
    #pragma unroll
    for (int i = 0; i < 4; i++) {      // stage A hi/lo planes
      int idx = tid + i*256;
      int kq = idx & 3, wl = (idx >> 2) & 127, pl = idx >> 9;
      const short* sp = (pl ? ATl : ATh) + (size_t)(w0 + wl)*1024 + k0 + kq*8;
      int4 v = *(const int4*)sp;
      *(int4*)&Asd[pl][wl*40 + kq*8] = v;
    }
    {                                  // stage B (bf16 already; no cvt)
      int s  = k0 >> 9;
      int v0 = k0 & 511;
      const u16* Ys = (s ? Y2h : Y1h) + (size_t)b*BSTR;
      #pragma unroll
      for (int i = 0; i < 2; i++) {
        int sel = g*2 + i;
        int oo = sel & 1, kq = sel >> 1;
        int o = mtile*2 + oo;
        u16 hs[8];
        #pragma unroll
        for (int j = 0; j < 8; j++) {
          int v = v0 + kq*8 + j;
          hs[j] = (v < N_) ? Ys[((size_t)o*N_ + v)*T_ + t_l] : (u16)0;
        }
        *(int4*)&Bsd[(oo*64 + t_l)*40 + kq*8] = *(const int4*)hs;
      }
    }
    __syncthreads();
    s8v bh[4];
    #pragma unroll
    for (int tj = 0; tj < 4; tj++) bh[tj] = *(const s8v*)&Bsd[offB[tj]];
    #pragma unroll
    for (int ti = 0; ti < 4; ti++) {
      s8v ah = *(const s8v*)&Asd[0][offA[ti]];
      s8v al = *(const s8v*)&Asd[1][offA[ti]];
      #pragma unroll
      for (int tj = 0; tj < 4; tj++) {
        f4v d = acc[ti*4+tj];
        d = __builtin_amdgcn_mfma_f32_16x16x32_bf16(ah, bh[tj], d, 0, 0, 0);
        d = __builtin_amdgcn_mfma_f32_16x16x32_bf16(al, bh[tj], d, 0, 0, 0);
        acc[ti*4+tj] = d;
      }
    }
  }

  // epilogue: out += acc; capture final values for next layer's BN stats.
  // All of a thread's tiles belong to one o (o = mtile*2 + wj).
  int o = mtile*2 + wj;
  float s = 0.f, s2 = 0.f;
  #pragma unroll
  for (int tj = 0; tj < 4; tj++) {
    int t = tj*16 + l15;
    float* obase = out + (((size_t)b*C_ + o)*N_)*T_ + t;
    #pragma unroll
    for (int ti = 0; ti < 4; ti++) {
      int wbase = w0 + wi*64 + ti*16 + quad*4;
      #pragma unroll
      for (int r = 0; r < 4; r++) {
        int w = wbase + r;
        if (w < N_) {
          float* p = obase + (size_t)w*T_;
          float val = *p + acc[ti*4+tj][r];
          *p = val;
          s += val;
          s2 = fmaf(val, val, s2);
        }
      }
    }
  }
  if (stp) {
    #pragma unroll
    for (int d = 32; d > 0; d >>= 1) {
      s  += __shfl_down(s,  d, 64);
      s2 += __shfl_down(s2, d, 64);
    }
    if (lane == 0) {
      atomicAdd(&stp[2*o],     (double)s);
      atomicAdd(&stp[2*o + 1], (double)s2);
    }
  }
}

// ---------------------------------------------------------------------------
// Online-softmax attention, one node per wave, MLP fully in registers.
// Weight streams are contiguous s_load_dwordx16 batches; no LDS.
__global__ __launch_bounds__(256) void attn3_kernel(
    const float* __restrict__ hsrc, float* __restrict__ O,
    float* __restrict__ sden,
    const float* __restrict__ W1T, const float* __restrict__ b1,
    const float* __restrict__ W2, const float* __restrict__ b2,
    const float* __restrict__ w3, const float* __restrict__ b3,
    int init)
{
  int tid = threadIdx.x;
  int t = tid & 63;
  int g = __builtin_amdgcn_readfirstlane(tid >> 6);
  int bx = blockIdx.x;
  int b = bx / 125;
  int n = (bx - b*125)*4 + g;
  size_t off = (size_t)b*BSTR + (size_t)n*T_;

  float h1r[64];
  #pragma unroll
  for (int k = 0; k < 64; k++) h1r[k] = b1[k];
  for (int c = 0; c < C_; c++) {
    float xv = fmaxf(hsrc[off + (size_t)c*CSTR + t], 0.f);
    const float* wr = W1T + c*64;
    #pragma unroll
    for (int k = 0; k < 64; k++) h1r[k] = fmaf(wr[k], xv, h1r[k]);
  }
  #pragma unroll
  for (int k = 0; k < 64; k++) h1r[k] = fmaxf(h1r[k], 0.f);

  float e = b3[0];
  for (int j = 0; j < 64; j++) {
    const float* w2r = W2 + j*64;
    float a0 = 0.f, a1 = 0.f, a2 = 0.f, a3 = 0.f;
    #pragma unroll
    for (int i = 0; i < 64; i += 4) {
      a0 = fmaf(w2r[i+0], h1r[i+0], a0);
      a1 = fmaf(w2r[i+1], h1r[i+1], a1);
      a2 = fmaf(w2r[i+2], h1r[i+2], a2);
      a3 = fmaf(w2r[i+3], h1r[i+3], a3);
    }
    float a = b2[j] + ((a0+a1)+(a2+a3));
    e = fmaf(w3[j], fmaxf(a, 0.f), e);
  }
  float p = expf(e);      // e is O(1): no max-subtraction needed

  size_t si = (size_t)b*CSTR + (size_t)n*T_ + t;
  float so = init ? 0.f : sden[si];
  sden[si] = so + p;

  for (int c = 0; c < C_; c++) {
    size_t pi = off + (size_t)c*CSTR + t;
    float xv = fmaxf(hsrc[pi], 0.f);      // L1-hit re-read
    float ov = init ? 0.f : O[pi];
    O[pi] = fmaf(p, xv, ov);
  }
}

// ---------------------------------------------------------------------------
__global__ __launch_bounds__(256) void norm_kernel(float* __restrict__ O,
                                                   const float* __restrict__ sden) {
  unsigned idx = (blockIdx.x*256u + threadIdx.x) * 4u;
  unsigned b = idx / BSTR;
  unsigned r = idx - b*BSTR;
  unsigned nt = r % CSTR;
  float4 o = *(float4*)(O + idx);
  const float* sp = sden + (size_t)b*CSTR + nt;
  o.x /= sp[0]; o.y /= sp[1]; o.z /= sp[2]; o.w /= sp[3];
  *(float4*)(O + idx) = o;
}

// ---------------------------------------------------------------------------
extern "C" void kernel_launch(void* const* d_in, const int* in_sizes, int n_in,
                              void* d_out, int out_size, void* d_ws, size_t ws_size,
                              hipStream_t stream)
{
  const float* x    = (const float*)d_in[0];
  const float* sup  = (const float*)d_in[1];
  const float* bng  = (const float*)d_in[2];
  const float* bnb  = (const float*)d_in[3];
  const float* rw   = (const float*)d_in[4];
  const float* rb   = (const float*)d_in[5];
  const float* aw   = (const float*)d_in[6];
  const float* ab   = (const float*)d_in[7];
  const float* gw   = (const float*)d_in[8];
  const float* gb   = (const float*)d_in[9];
  const float* gcw  = (const float*)d_in[10];
  const float* gcb  = (const float*)d_in[11];
  const float* w1   = (const float*)d_in[12];
  const float* ab1  = (const float*)d_in[13];
  const float* w2   = (const float*)d_in[14];
  const float* ab2  = (const float*)d_in[15];
  const float* w3   = (const float*)d_in[16];
  const float* ab3  = (const float*)d_in[17];
  float* out = (float*)d_out;

  float* ws   = (float*)d_ws;
  float* bufA = ws;                       // Y0 / layer output h (float)
  u16*   Y1h  = (u16*)(ws + TENS);        // bf16 Y1 plane
  u16*   Y2h  = Y1h + TENS;               // bf16 Y2 plane
  float* sden = ws + (size_t)3*TENS;      // [B,N,T] softmax denom
  double* st  = (double*)(ws + (size_t)3*TENS + (size_t)B_*N_*T_);
  short* ATh  = (short*)(ws + (size_t)3*TENS + (size_t)B_*N_*T_ + 512);
  short* ATl  = ATh + (size_t)512*1024;
  float* W1T  = (float*)(ATl + (size_t)512*1024);

  zero_kernel<<<1, 256, 0, stream>>>(st);
  aconv_kernel<<<2048, 256, 0, stream>>>(sup, ATh, ATl);
  w1t_kernel<<<8, 256, 0, stream>>>(w1, W1T);
  stats_kernel<<<dim3(C_, B_), 256, 0, stream>>>(x, st);
  // slot 0 of the stack = x
  attn3_kernel<<<B_*125, 256, 0, stream>>>(x, out, sden, W1T, ab1, w2, ab2, w3, ab3, 1);

  const float* hcur = x;
  for (int l = 0; l < L_; l++) {
    fuse3_kernel<<<B_*250, 512, 0, stream>>>(
        hcur, st + l*64, bng + l*C_, bnb + l*C_,
        rw + l*C_*C_, rb + l*C_,
        aw + l*C_*C_*3, ab + l*C_,
        gw + l*C_*C_*3, gb + l*C_,
        gcw + l*C_*96, gcb + l*C_,
        bufA, Y1h, Y2h);
    diff3_kernel<<<dim3(64, B_), 256, 0, stream>>>(
        Y1h, Y2h, ATh, ATl, bufA, (l < L_-1) ? (st + (l+1)*64) : nullptr);
    attn3_kernel<<<B_*125, 256, 0, stream>>>(bufA, out, sden, W1T, ab1, w2, ab2, w3, ab3, 0);
    hcur = bufA;
  }
  norm_kernel<<<16000, 256, 0, stream>>>(out, sden);
}

// Round 3
// 1672.059 us; speedup vs baseline: 1.4102x; 1.2206x over previous
//
#include <hip/hip_runtime.h>
#include <hip/hip_bf16.h>
#include <math.h>

#define B_ 16
#define C_ 32
#define N_ 500
#define T_ 64
#define L_ 4
#define BSTR (C_*N_*T_)              // 1024000
#define CSTR (N_*T_)                 // 32000
#define TENS ((size_t)B_*C_*N_*T_)   // 16384000
#define CNT_ 512000.0

typedef short s8v __attribute__((ext_vector_type(8)));
typedef float f4v __attribute__((ext_vector_type(4)));
typedef unsigned short u16;

// ---------------------------------------------------------------------------
__global__ __launch_bounds__(256) void zero_kernel(double* __restrict__ p) {
  p[threadIdx.x] = 0.0;   // 256 doubles = L_*64 stats slots
}

// ---------------------------------------------------------------------------
// Per-channel sum/sum-sq for BN, layer 0 only (reads x). fp64 exact.
__global__ __launch_bounds__(256) void stats_kernel(const float* __restrict__ h,
                                                    double* __restrict__ st) {
  int c = blockIdx.x, b = blockIdx.y, tid = threadIdx.x;
  const float4* p = (const float4*)(h + (size_t)b*BSTR + (size_t)c*CSTR);
  double s = 0.0, s2 = 0.0;
  for (int i = tid; i < CSTR/4; i += 256) {
    float4 v = p[i];
    s  += (double)v.x + (double)v.y + (double)v.z + (double)v.w;
    s2 += (double)v.x*v.x + (double)v.y*v.y + (double)v.z*v.z + (double)v.w*v.w;
  }
  __shared__ double sd[256], sd2[256];
  sd[tid] = s; sd2[tid] = s2; __syncthreads();
  for (int off = 128; off > 0; off >>= 1) {
    if (tid < off) { sd[tid] += sd[tid+off]; sd2[tid] += sd2[tid+off]; }
    __syncthreads();
  }
  if (tid == 0) { atomicAdd(&st[2*c], sd[0]); atomicAdd(&st[2*c+1], sd2[0]); }
}

// ---------------------------------------------------------------------------
// Build ATcat[w][k] bf16 hi/lo planes, w<512 (pad), k<1024 (two 512 supports).
__global__ __launch_bounds__(256) void aconv_kernel(const float* __restrict__ sup,
                                                    short* __restrict__ ATh,
                                                    short* __restrict__ ATl) {
  int idx = blockIdx.x*256 + threadIdx.x;   // 512*1024
  int k = idx & 1023, w = idx >> 10;
  int s = k >> 9, v = k & 511;
  float val = (v < N_ && w < N_) ? sup[((size_t)s*N_ + v)*N_ + w] : 0.f;
  __hip_bfloat16 bh = __float2bfloat16(val);
  float fh = __bfloat162float(bh);
  __hip_bfloat16 bl = __float2bfloat16(val - fh);
  ATh[idx] = *(short*)&bh;
  ATl[idx] = *(short*)&bl;
}

// ---------------------------------------------------------------------------
// One-time W1 transpose: W1T[c][k] = W1[k][c], 2048 elems.
__global__ __launch_bounds__(256) void w1t_kernel(const float* __restrict__ W1,
                                                  float* __restrict__ W1T) {
  int idx = blockIdx.x*256 + threadIdx.x;   // 2048
  int c = idx >> 6, k = idx & 63;
  W1T[c*64 + k] = W1[k*32 + c];
}

// ---------------------------------------------------------------------------
// Weight prep for MFMA fuse4: B-fragment layouts [col][k=c] bf16 hi/lo.
// WAG[l][tap][col(64: 0-31 aff, 32-63 gate)][c(32)], WR[l][o(32)][c(32)].
__global__ __launch_bounds__(256) void wprep_kernel(
    const float* __restrict__ aw, const float* __restrict__ gw,
    const float* __restrict__ rw,
    u16* __restrict__ wagh, u16* __restrict__ wagl,
    u16* __restrict__ wrh,  u16* __restrict__ wrl)
{
  int idx = blockIdx.x*256 + threadIdx.x;   // 0..28671
  if (idx >= 28672) return;
  float v; u16 *dh, *dl; int di;
  if (idx < 24576) {
    int l = idx / 6144, r = idx % 6144;
    int tap = r / 2048, col = (r >> 5) & 63, c = r & 31;
    v = (col < 32) ? aw[l*3072 + (col*32 + c)*3 + tap]
                   : gw[l*3072 + ((col-32)*32 + c)*3 + tap];
    dh = wagh; dl = wagl; di = idx;
  } else {
    int j = idx - 24576;
    int l = j >> 10, o = (j >> 5) & 31, c = j & 31;
    v = rw[l*1024 + o*32 + c];
    dh = wrh; dl = wrl; di = j;
  }
  __hip_bfloat16 bh = __float2bfloat16(v);
  float fh = __bfloat162float(bh);
  __hip_bfloat16 bl = __float2bfloat16(v - fh);
  dh[di] = *(u16*)&bh;
  dl[di] = *(u16*)&bl;
}

// ---------------------------------------------------------------------------
// MFMA fuse: BN -> ReLU -> split-bf16 {res 1x1, causal convs K=3} on matrix
// cores (3-product split = ~fp32 exact) -> tanh*sigmoid in C-fragments ->
// z to LDS -> VALU 32x96 mix (proven epilogue). 2 nodes/block, 8 waves,
// one 16-row m-tile per wave. Y0 may alias input h (reads fully staged).
__global__ __launch_bounds__(512) void fuse4_kernel(
    const float* __restrict__ h, const double* __restrict__ st,
    const float* __restrict__ gamma, const float* __restrict__ beta,
    const u16* __restrict__ wagh, const u16* __restrict__ wagl,
    const u16* __restrict__ wrh,  const u16* __restrict__ wrl,
    const float* __restrict__ rb, const float* __restrict__ ab,
    const float* __restrict__ gb,
    const float* __restrict__ gcw, const float* __restrict__ gcb,
    float* __restrict__ Y0, u16* __restrict__ Y1h, u16* __restrict__ Y2h)
{
  __shared__ __align__(16) char smem[41600];
  __shared__ float ssc[C_], ssb[C_];
  u16* Sxh = (u16*)smem;          // x planes [132 rows][40] (2 pad rows/node)
  u16* Sxl = Sxh + 5280;
  u16* Shh = Sxl + 5280;          // h planes [128][40]
  u16* Shl = Shh + 5120;
  float* Sz = (float*)smem;       // overlay after GEMM: z [2][32*65]

  int tid = threadIdx.x;
  int bx  = blockIdx.x;
  int b = bx / 250, np = bx - b*250;
  size_t off0 = (size_t)b*BSTR + (size_t)(np*2)*T_;

  // ---- stage: 8 f32/thread (coalesced: consecutive tid -> consecutive m)
  int m  = tid & 127;             // m = nn*64 + t  (T_=64)
  int c0 = (tid >> 7) << 3;       // 8-channel group
  float hv[8];
  #pragma unroll
  for (int j = 0; j < 8; j++)
    hv[j] = h[off0 + (size_t)(c0 + j)*CSTR + m];

  if (tid < C_) {
    double mm = st[2*tid] * (1.0/CNT_);
    double vv = st[2*tid+1] * (1.0/CNT_) - mm*mm;
    float sc = gamma[tid] * (float)(1.0 / sqrt(vv + 1e-5));
    ssc[tid] = sc;
    ssb[tid] = beta[tid] - (float)mm * sc;
  }
  __syncthreads();

  union P { u16 s[8]; int4 v; };
  P hh8, hl8, xh8, xl8;
  #pragma unroll
  for (int j = 0; j < 8; j++) {
    float hval = hv[j];
    __hip_bfloat16 t1 = __float2bfloat16(hval);
    hh8.s[j] = *(u16*)&t1;
    __hip_bfloat16 t2 = __float2bfloat16(hval - __bfloat162float(t1));
    hl8.s[j] = *(u16*)&t2;
    float xval = fmaxf(fmaf(hval, ssc[c0+j], ssb[c0+j]), 0.f);
    __hip_bfloat16 t3 = __float2bfloat16(xval);
    xh8.s[j] = *(u16*)&t3;
    __hip_bfloat16 t4 = __float2bfloat16(xval - __bfloat162float(t3));
    xl8.s[j] = *(u16*)&t4;
  }
  *(int4*)&Shh[m*40 + c0] = hh8.v;
  *(int4*)&Shl[m*40 + c0] = hl8.v;
  int xrow = m + 2 + (m >> 6)*2;  // node*66 + tloc + 2
  *(int4*)&Sxh[xrow*40 + c0] = xh8.v;
  *(int4*)&Sxl[xrow*40 + c0] = xl8.v;
  if (tid < 32) {                 // zero pad rows {0,1,66,67} x 2 planes
    int pl = tid >> 4, rsel = (tid >> 2) & 3, ch = tid & 3;
    int row = (rsel & 1) + (rsel >> 1)*66;
    int4 z4 = {0,0,0,0};
    *(int4*)((pl ? Sxl : Sxh) + row*40 + ch*8) = z4;
  }
  __syncthreads();

  // ---- GEMM phase: wave -> 16-row m-tile (node, t0), all 32 out channels
  int lane = tid & 63;
  int wave = __builtin_amdgcn_readfirstlane(tid >> 6);
  int node = wave >> 2, t0 = (wave & 3) << 4;
  int l15 = lane & 15, q = lane >> 4;

  f4v affc[2], gatec[2], resc[2];
  #pragma unroll
  for (int i = 0; i < 2; i++) {
    affc[i] = (f4v){0.f,0.f,0.f,0.f};
    gatec[i] = (f4v){0.f,0.f,0.f,0.f};
    resc[i] = (f4v){0.f,0.f,0.f,0.f};
  }

  {   // res: A = h planes, K=32
    int ha = (node*64 + t0 + l15)*40 + q*8;
    s8v hhf = *(const s8v*)&Shh[ha];
    s8v hlf = *(const s8v*)&Shl[ha];
    #pragma unroll
    for (int ct = 0; ct < 2; ct++) {
      int wb = (ct*16 + l15)*32 + q*8;
      s8v wh = *(const s8v*)&wrh[wb];
      s8v wl = *(const s8v*)&wrl[wb];
      f4v d = resc[ct];
      d = __builtin_amdgcn_mfma_f32_16x16x32_bf16(hhf, wh, d, 0, 0, 0);
      d = __builtin_amdgcn_mfma_f32_16x16x32_bf16(hlf, wh, d, 0, 0, 0);
      d = __builtin_amdgcn_mfma_f32_16x16x32_bf16(hhf, wl, d, 0, 0, 0);
      resc[ct] = d;
    }
  }
  #pragma unroll
  for (int tap = 0; tap < 3; tap++) {   // causal conv = 3 shifted-row GEMMs
    int xa = (node*66 + t0 + l15 + tap)*40 + q*8;
    s8v xhf = *(const s8v*)&Sxh[xa];
    s8v xlf = *(const s8v*)&Sxl[xa];
    #pragma unroll
    for (int ct = 0; ct < 4; ct++) {    // 0,1 aff cols; 2,3 gate cols
      int wb = (tap*64 + ct*16 + l15)*32 + q*8;
      s8v wh = *(const s8v*)&wagh[wb];
      s8v wl = *(const s8v*)&wagl[wb];
      f4v d = (ct < 2) ? affc[ct] : gatec[ct-2];
      d = __builtin_amdgcn_mfma_f32_16x16x32_bf16(xhf, wh, d, 0, 0, 0);
      d = __builtin_amdgcn_mfma_f32_16x16x32_bf16(xlf, wh, d, 0, 0, 0);
      d = __builtin_amdgcn_mfma_f32_16x16x32_bf16(xhf, wl, d, 0, 0, 0);
      if (ct < 2) affc[ct] = d; else gatec[ct-2] = d;
    }
  }
  __syncthreads();   // all LDS A-reads done before z overlays the planes

  // ---- combine in C-fragment layout: col=o=l15(+16ct), row m=t0+q*4+r
  #pragma unroll
  for (int ct = 0; ct < 2; ct++) {
    int o = ct*16 + l15;
    float abias = ab[o] + rb[o];
    float gbias = gb[o];
    #pragma unroll
    for (int r = 0; r < 4; r++) {
      float a = affc[ct][r] + resc[ct][r] + abias;
      float g = gatec[ct][r] + gbias;
      float z = tanhf(a) * (1.f/(1.f + expf(-g)));
      Sz[node*2080 + o*65 + (t0 + q*4 + r)] = z;
    }
  }
  __syncthreads();

  // ---- mix: three 32x32 pointwise GEMMs on VALU (proven epilogue)
  int t = tid & 63;
  int og = wave;
  float y0a[2][4] = {}, y1a[2][4] = {}, y2a[2][4] = {};
  for (int c = 0; c < C_; c++) {
    float g0[4], g1[4], g2[4];
    #pragma unroll
    for (int jq = 0; jq < 4; jq++) {
      const float* gr = gcw + (og*4 + jq)*96;
      g0[jq] = gr[c]; g1[jq] = gr[32 + c]; g2[jq] = gr[64 + c];
    }
    #pragma unroll
    for (int nn = 0; nn < 2; nn++) {
      float zc = Sz[nn*2080 + c*65 + t];
      #pragma unroll
      for (int jq = 0; jq < 4; jq++) {
        y0a[nn][jq] = fmaf(g0[jq], zc, y0a[nn][jq]);
        y1a[nn][jq] = fmaf(g1[jq], zc, y1a[nn][jq]);
        y2a[nn][jq] = fmaf(g2[jq], zc, y2a[nn][jq]);
      }
    }
  }
  #pragma unroll
  for (int nn = 0; nn < 2; nn++)
    #pragma unroll
    for (int jq = 0; jq < 4; jq++) {
      int oo = og*4 + jq;
      size_t pp = off0 + (size_t)nn*T_ + (size_t)oo*CSTR + t;
      Y0[pp] = y0a[nn][jq] + gcb[oo];
      __hip_bfloat16 b1 = __float2bfloat16(y1a[nn][jq]);
      __hip_bfloat16 b2 = __float2bfloat16(y2a[nn][jq]);
      Y1h[pp] = *(u16*)&b1;
      Y2h[pp] = *(u16*)&b2;
    }
}

// ---------------------------------------------------------------------------
// Diffusion: A split-bf16 (hi+lo) x B single-plane bf16 -> 2 MFMA per tile.
// Proven two-barrier schedule. Fused next-layer BN stats in the epilogue.
__global__ __launch_bounds__(256) void diff3_kernel(
    const u16* __restrict__ Y1h, const u16* __restrict__ Y2h,
    const short* __restrict__ ATh, const short* __restrict__ ATl,
    float* __restrict__ out, double* __restrict__ stp)
{
  __shared__ short Asd[2][128*40];   // AT tile [plane][w_local][k(32)+pad8]
  __shared__ short Bsd[128*40];      // Y  tile [m_local][k(32)+pad8], bf16 hi only

  int tid = threadIdx.x;
  int bx = blockIdx.x;
  int mtile = bx & 15, wtile = bx >> 4;
  int b = blockIdx.y;
  int w0 = wtile << 7;

  int lane = tid & 63;
  int wave = __builtin_amdgcn_readfirstlane(tid >> 6);
  int wi = wave & 1, wj = wave >> 1;
  int l15 = lane & 15, quad = lane >> 4;

  int offA[4], offB[4];
  #pragma unroll
  for (int ti = 0; ti < 4; ti++) offA[ti] = (wi*64 + ti*16 + l15)*40 + quad*8;
  #pragma unroll
  for (int tj = 0; tj < 4; tj++) offB[tj] = (wj*64 + tj*16 + l15)*40 + quad*8;

  f4v acc[16];
  #pragma unroll
  for (int i = 0; i < 16; i++) acc[i] = (f4v){0.f, 0.f, 0.f, 0.f};

  int t_l = tid & 63;
  int g = tid >> 6;

  for (int k0 = 0; k0 < 1024; k0 += 32) {
    __syncthreads();
    #pragma unroll
    for (int i = 0; i < 4; i++) {      // stage A hi/lo planes
      int idx = tid + i*256;
      int kq = idx & 3, wl = (idx >> 2) & 127, pl = idx >> 9;
      const short* sp = (pl ? ATl : ATh) + (size_t)(w0 + wl)*1024 + k0 + kq*8;
      int4 v = *(const int4*)sp;
      *(int4*)&Asd[pl][wl*40 + kq*8] = v;
    }
    {                                  // stage B (bf16 already; no cvt)
      int s  = k0 >> 9;
      int v0 = k0 & 511;
      const u16* Ys = (s ? Y2h : Y1h) + (size_t)b*BSTR;
      #pragma unroll
      for (int i = 0; i < 2; i++) {
        int sel = g*2 + i;
        int oo = sel & 1, kq = sel >> 1;
        int o = mtile*2 + oo;
        u16 hs[8];
        #pragma unroll
        for (int j = 0; j < 8; j++) {
          int v = v0 + kq*8 + j;
          hs[j] = (v < N_) ? Ys[((size_t)o*N_ + v)*T_ + t_l] : (u16)0;
        }
        *(int4*)&Bsd[(oo*64 + t_l)*40 + kq*8] = *(const int4*)hs;
      }
    }
    __syncthreads();
    s8v bh[4];
    #pragma unroll
    for (int tj = 0; tj < 4; tj++) bh[tj] = *(const s8v*)&Bsd[offB[tj]];
    #pragma unroll
    for (int ti = 0; ti < 4; ti++) {
      s8v ah = *(const s8v*)&Asd[0][offA[ti]];
      s8v al = *(const s8v*)&Asd[1][offA[ti]];
      #pragma unroll
      for (int tj = 0; tj < 4; tj++) {
        f4v d = acc[ti*4+tj];
        d = __builtin_amdgcn_mfma_f32_16x16x32_bf16(ah, bh[tj], d, 0, 0, 0);
        d = __builtin_amdgcn_mfma_f32_16x16x32_bf16(al, bh[tj], d, 0, 0, 0);
        acc[ti*4+tj] = d;
      }
    }
  }

  // epilogue: out += acc; capture final values for next layer's BN stats.
  int o = mtile*2 + wj;
  float s = 0.f, s2 = 0.f;
  #pragma unroll
  for (int tj = 0; tj < 4; tj++) {
    int t = tj*16 + l15;
    float* obase = out + (((size_t)b*C_ + o)*N_)*T_ + t;
    #pragma unroll
    for (int ti = 0; ti < 4; ti++) {
      int wbase = w0 + wi*64 + ti*16 + quad*4;
      #pragma unroll
      for (int r = 0; r < 4; r++) {
        int w = wbase + r;
        if (w < N_) {
          float* p = obase + (size_t)w*T_;
          float val = *p + acc[ti*4+tj][r];
          *p = val;
          s += val;
          s2 = fmaf(val, val, s2);
        }
      }
    }
  }
  if (stp) {
    #pragma unroll
    for (int d = 32; d > 0; d >>= 1) {
      s  += __shfl_down(s,  d, 64);
      s2 += __shfl_down(s2, d, 64);
    }
    if (lane == 0) {
      atomicAdd(&stp[2*o],     (double)s);
      atomicAdd(&stp[2*o + 1], (double)s2);
    }
  }
}

// ---------------------------------------------------------------------------
// Online-softmax attention, one node per wave, MLP fully in registers.
__global__ __launch_bounds__(256) void attn3_kernel(
    const float* __restrict__ hsrc, float* __restrict__ O,
    float* __restrict__ sden,
    const float* __restrict__ W1T, const float* __restrict__ b1,
    const float* __restrict__ W2, const float* __restrict__ b2,
    const float* __restrict__ w3, const float* __restrict__ b3,
    int init)
{
  int tid = threadIdx.x;
  int t = tid & 63;
  int g = __builtin_amdgcn_readfirstlane(tid >> 6);
  int bx = blockIdx.x;
  int b = bx / 125;
  int n = (bx - b*125)*4 + g;
  size_t off = (size_t)b*BSTR + (size_t)n*T_;

  float h1r[64];
  #pragma unroll
  for (int k = 0; k < 64; k++) h1r[k] = b1[k];
  for (int c = 0; c < C_; c++) {
    float xv = fmaxf(hsrc[off + (size_t)c*CSTR + t], 0.f);
    const float* wr = W1T + c*64;
    #pragma unroll
    for (int k = 0; k < 64; k++) h1r[k] = fmaf(wr[k], xv, h1r[k]);
  }
  #pragma unroll
  for (int k = 0; k < 64; k++) h1r[k] = fmaxf(h1r[k], 0.f);

  float e = b3[0];
  for (int j = 0; j < 64; j++) {
    const float* w2r = W2 + j*64;
    float a0 = 0.f, a1 = 0.f, a2 = 0.f, a3 = 0.f;
    #pragma unroll
    for (int i = 0; i < 64; i += 4) {
      a0 = fmaf(w2r[i+0], h1r[i+0], a0);
      a1 = fmaf(w2r[i+1], h1r[i+1], a1);
      a2 = fmaf(w2r[i+2], h1r[i+2], a2);
      a3 = fmaf(w2r[i+3], h1r[i+3], a3);
    }
    float a = b2[j] + ((a0+a1)+(a2+a3));
    e = fmaf(w3[j], fmaxf(a, 0.f), e);
  }
  float p = expf(e);      // e is O(1): no max-subtraction needed

  size_t si = (size_t)b*CSTR + (size_t)n*T_ + t;
  float so = init ? 0.f : sden[si];
  sden[si] = so + p;

  for (int c = 0; c < C_; c++) {
    size_t pi = off + (size_t)c*CSTR + t;
    float xv = fmaxf(hsrc[pi], 0.f);      // L1-hit re-read
    float ov = init ? 0.f : O[pi];
    O[pi] = fmaf(p, xv, ov);
  }
}

// ---------------------------------------------------------------------------
__global__ __launch_bounds__(256) void norm_kernel(float* __restrict__ O,
                                                   const float* __restrict__ sden) {
  unsigned idx = (blockIdx.x*256u + threadIdx.x) * 4u;
  unsigned b = idx / BSTR;
  unsigned r = idx - b*BSTR;
  unsigned nt = r % CSTR;
  float4 o = *(float4*)(O + idx);
  const float* sp = sden + (size_t)b*CSTR + nt;
  o.x /= sp[0]; o.y /= sp[1]; o.z /= sp[2]; o.w /= sp[3];
  *(float4*)(O + idx) = o;
}

// ---------------------------------------------------------------------------
extern "C" void kernel_launch(void* const* d_in, const int* in_sizes, int n_in,
                              void* d_out, int out_size, void* d_ws, size_t ws_size,
                              hipStream_t stream)
{
  const float* x    = (const float*)d_in[0];
  const float* sup  = (const float*)d_in[1];
  const float* bng  = (const float*)d_in[2];
  const float* bnb  = (const float*)d_in[3];
  const float* rw   = (const float*)d_in[4];
  const float* rb   = (const float*)d_in[5];
  const float* aw   = (const float*)d_in[6];
  const float* ab   = (const float*)d_in[7];
  const float* gw   = (const float*)d_in[8];
  const float* gb   = (const float*)d_in[9];
  const float* gcw  = (const float*)d_in[10];
  const float* gcb  = (const float*)d_in[11];
  const float* w1   = (const float*)d_in[12];
  const float* ab1  = (const float*)d_in[13];
  const float* w2   = (const float*)d_in[14];
  const float* ab2  = (const float*)d_in[15];
  const float* w3   = (const float*)d_in[16];
  const float* ab3  = (const float*)d_in[17];
  float* out = (float*)d_out;

  float* ws   = (float*)d_ws;
  float* bufA = ws;                       // Y0 / layer output h (float)
  u16*   Y1h  = (u16*)(ws + TENS);        // bf16 Y1 plane
  u16*   Y2h  = Y1h + TENS;               // bf16 Y2 plane
  float* sden = ws + (size_t)3*TENS;      // [B,N,T] softmax denom
  double* st  = (double*)(ws + (size_t)3*TENS + (size_t)B_*N_*T_);
  short* ATh  = (short*)(ws + (size_t)3*TENS + (size_t)B_*N_*T_ + 512);
  short* ATl  = ATh + (size_t)512*1024;
  float* W1T  = (float*)(ATl + (size_t)512*1024);
  u16* WAGh = (u16*)(W1T + 2048);         // [L][3][64][32]
  u16* WAGl = WAGh + 24576;
  u16* WRh  = WAGl + 24576;               // [L][32][32]
  u16* WRl  = WRh + 4096;

  zero_kernel<<<1, 256, 0, stream>>>(st);
  aconv_kernel<<<2048, 256, 0, stream>>>(sup, ATh, ATl);
  w1t_kernel<<<8, 256, 0, stream>>>(w1, W1T);
  wprep_kernel<<<112, 256, 0, stream>>>(aw, gw, rw, WAGh, WAGl, WRh, WRl);
  stats_kernel<<<dim3(C_, B_), 256, 0, stream>>>(x, st);
  // slot 0 of the stack = x
  attn3_kernel<<<B_*125, 256, 0, stream>>>(x, out, sden, W1T, ab1, w2, ab2, w3, ab3, 1);

  const float* hcur = x;
  for (int l = 0; l < L_; l++) {
    fuse4_kernel<<<B_*250, 512, 0, stream>>>(
        hcur, st + l*64, bng + l*C_, bnb + l*C_,
        WAGh + l*6144, WAGl + l*6144, WRh + l*1024, WRl + l*1024,
        rb + l*C_, ab + l*C_, gb + l*C_,
        gcw + l*C_*96, gcb + l*C_,
        bufA, Y1h, Y2h);
    diff3_kernel<<<dim3(64, B_), 256, 0, stream>>>(
        Y1h, Y2h, ATh, ATl, bufA, (l < L_-1) ? (st + (l+1)*64) : nullptr);
    attn3_kernel<<<B_*125, 256, 0, stream>>>(bufA, out, sden, W1T, ab1, w2, ab2, w3, ab3, 0);
    hcur = bufA;
  }
  norm_kernel<<<16000, 256, 0, stream>>>(out, sden);
}

// Round 4
// 1617.895 us; speedup vs baseline: 1.4575x; 1.0335x over previous
//
#include <hip/hip_runtime.h>
#include <hip/hip_bf16.h>
#include <math.h>

#define B_ 16
#define C_ 32
#define N_ 500
#define T_ 64
#define L_ 4
#define BSTR (C_*N_*T_)              // 1024000
#define CSTR (N_*T_)                 // 32000
#define TENS ((size_t)B_*C_*N_*T_)   // 16384000
#define CNT_ 512000.0

typedef short s8v __attribute__((ext_vector_type(8)));
typedef float f4v __attribute__((ext_vector_type(4)));
typedef unsigned short u16;

// ---------------------------------------------------------------------------
__global__ __launch_bounds__(256) void zero_kernel(double* __restrict__ p) {
  p[threadIdx.x] = 0.0;   // 256 doubles = L_*64 stats slots
}

// ---------------------------------------------------------------------------
// Per-channel sum/sum-sq for BN, layer 0 only (reads x). fp64 exact.
__global__ __launch_bounds__(256) void stats_kernel(const float* __restrict__ h,
                                                    double* __restrict__ st) {
  int c = blockIdx.x, b = blockIdx.y, tid = threadIdx.x;
  const float4* p = (const float4*)(h + (size_t)b*BSTR + (size_t)c*CSTR);
  double s = 0.0, s2 = 0.0;
  for (int i = tid; i < CSTR/4; i += 256) {
    float4 v = p[i];
    s  += (double)v.x + (double)v.y + (double)v.z + (double)v.w;
    s2 += (double)v.x*v.x + (double)v.y*v.y + (double)v.z*v.z + (double)v.w*v.w;
  }
  __shared__ double sd[256], sd2[256];
  sd[tid] = s; sd2[tid] = s2; __syncthreads();
  for (int off = 128; off > 0; off >>= 1) {
    if (tid < off) { sd[tid] += sd[tid+off]; sd2[tid] += sd2[tid+off]; }
    __syncthreads();
  }
  if (tid == 0) { atomicAdd(&st[2*c], sd[0]); atomicAdd(&st[2*c+1], sd2[0]); }
}

// ---------------------------------------------------------------------------
// Build ATcat[w][k] bf16 hi/lo planes, w<512 (pad), k<1024 (two 512 supports).
__global__ __launch_bounds__(256) void aconv_kernel(const float* __restrict__ sup,
                                                    short* __restrict__ ATh,
                                                    short* __restrict__ ATl) {
  int idx = blockIdx.x*256 + threadIdx.x;   // 512*1024
  int k = idx & 1023, w = idx >> 10;
  int s = k >> 9, v = k & 511;
  float val = (v < N_ && w < N_) ? sup[((size_t)s*N_ + v)*N_ + w] : 0.f;
  __hip_bfloat16 bh = __float2bfloat16(val);
  float fh = __bfloat162float(bh);
  __hip_bfloat16 bl = __float2bfloat16(val - fh);
  ATh[idx] = *(short*)&bh;
  ATl[idx] = *(short*)&bl;
}

// ---------------------------------------------------------------------------
// One-time W1 transpose: W1T[c][k] = W1[k][c], 2048 elems.
__global__ __launch_bounds__(256) void w1t_kernel(const float* __restrict__ W1,
                                                  float* __restrict__ W1T) {
  int idx = blockIdx.x*256 + threadIdx.x;   // 2048
  int c = idx >> 6, k = idx & 63;
  W1T[c*64 + k] = W1[k*32 + c];
}

// ---------------------------------------------------------------------------
// Weight prep for MFMA fuse4: B-fragment layouts [col][k=c] bf16 hi/lo.
// WAG[l][tap][col(64: 0-31 aff, 32-63 gate)][c(32)], WR[l][o(32)][c(32)].
__global__ __launch_bounds__(256) void wprep_kernel(
    const float* __restrict__ aw, const float* __restrict__ gw,
    const float* __restrict__ rw,
    u16* __restrict__ wagh, u16* __restrict__ wagl,
    u16* __restrict__ wrh,  u16* __restrict__ wrl)
{
  int idx = blockIdx.x*256 + threadIdx.x;   // 0..28671
  if (idx >= 28672) return;
  float v; u16 *dh, *dl; int di;
  if (idx < 24576) {
    int l = idx / 6144, r = idx % 6144;
    int tap = r / 2048, col = (r >> 5) & 63, c = r & 31;
    v = (col < 32) ? aw[l*3072 + (col*32 + c)*3 + tap]
                   : gw[l*3072 + ((col-32)*32 + c)*3 + tap];
    dh = wagh; dl = wagl; di = idx;
  } else {
    int j = idx - 24576;
    int l = j >> 10, o = (j >> 5) & 31, c = j & 31;
    v = rw[l*1024 + o*32 + c];
    dh = wrh; dl = wrl; di = j;
  }
  __hip_bfloat16 bh = __float2bfloat16(v);
  float fh = __bfloat162float(bh);
  __hip_bfloat16 bl = __float2bfloat16(v - fh);
  dh[di] = *(u16*)&bh;
  dl[di] = *(u16*)&bl;
}

// ---------------------------------------------------------------------------
// MFMA fuse: BN -> ReLU -> split-bf16 {res 1x1, causal convs K=3} on matrix
// cores (3-product split = ~fp32 exact) -> tanh*sigmoid in C-fragments ->
// z to LDS -> VALU 32x96 mix (proven epilogue). 2 nodes/block, 8 waves,
// one 16-row m-tile per wave. Y0 may alias input h (reads fully staged).
__global__ __launch_bounds__(512) void fuse4_kernel(
    const float* __restrict__ h, const double* __restrict__ st,
    const float* __restrict__ gamma, const float* __restrict__ beta,
    const u16* __restrict__ wagh, const u16* __restrict__ wagl,
    const u16* __restrict__ wrh,  const u16* __restrict__ wrl,
    const float* __restrict__ rb, const float* __restrict__ ab,
    const float* __restrict__ gb,
    const float* __restrict__ gcw, const float* __restrict__ gcb,
    float* __restrict__ Y0, u16* __restrict__ Y1h, u16* __restrict__ Y2h)
{
  __shared__ __align__(16) char smem[41600];
  __shared__ float ssc[C_], ssb[C_];
  u16* Sxh = (u16*)smem;          // x planes [132 rows][40] (2 pad rows/node)
  u16* Sxl = Sxh + 5280;
  u16* Shh = Sxl + 5280;          // h planes [128][40]
  u16* Shl = Shh + 5120;
  float* Sz = (float*)smem;       // overlay after GEMM: z [2][32*65]

  int tid = threadIdx.x;
  int bx  = blockIdx.x;
  int b = bx / 250, np = bx - b*250;
  size_t off0 = (size_t)b*BSTR + (size_t)(np*2)*T_;

  // ---- stage: 8 f32/thread (coalesced: consecutive tid -> consecutive m)
  int m  = tid & 127;             // m = nn*64 + t  (T_=64)
  int c0 = (tid >> 7) << 3;       // 8-channel group
  float hv[8];
  #pragma unroll
  for (int j = 0; j < 8; j++)
    hv[j] = h[off0 + (size_t)(c0 + j)*CSTR + m];

  if (tid < C_) {
    double mm = st[2*tid] * (1.0/CNT_);
    double vv = st[2*tid+1] * (1.0/CNT_) - mm*mm;
    float sc = gamma[tid] * (float)(1.0 / sqrt(vv + 1e-5));
    ssc[tid] = sc;
    ssb[tid] = beta[tid] - (float)mm * sc;
  }
  __syncthreads();

  union P { u16 s[8]; int4 v; };
  P hh8, hl8, xh8, xl8;
  #pragma unroll
  for (int j = 0; j < 8; j++) {
    float hval = hv[j];
    __hip_bfloat16 t1 = __float2bfloat16(hval);
    hh8.s[j] = *(u16*)&t1;
    __hip_bfloat16 t2 = __float2bfloat16(hval - __bfloat162float(t1));
    hl8.s[j] = *(u16*)&t2;
    float xval = fmaxf(fmaf(hval, ssc[c0+j], ssb[c0+j]), 0.f);
    __hip_bfloat16 t3 = __float2bfloat16(xval);
    xh8.s[j] = *(u16*)&t3;
    __hip_bfloat16 t4 = __float2bfloat16(xval - __bfloat162float(t3));
    xl8.s[j] = *(u16*)&t4;
  }
  *(int4*)&Shh[m*40 + c0] = hh8.v;
  *(int4*)&Shl[m*40 + c0] = hl8.v;
  int xrow = m + 2 + (m >> 6)*2;  // node*66 + tloc + 2
  *(int4*)&Sxh[xrow*40 + c0] = xh8.v;
  *(int4*)&Sxl[xrow*40 + c0] = xl8.v;
  if (tid < 32) {                 // zero pad rows {0,1,66,67} x 2 planes
    int pl = tid >> 4, rsel = (tid >> 2) & 3, ch = tid & 3;
    int row = (rsel & 1) + (rsel >> 1)*66;
    int4 z4 = {0,0,0,0};
    *(int4*)((pl ? Sxl : Sxh) + row*40 + ch*8) = z4;
  }
  __syncthreads();

  // ---- GEMM phase: wave -> 16-row m-tile (node, t0), all 32 out channels
  int lane = tid & 63;
  int wave = __builtin_amdgcn_readfirstlane(tid >> 6);
  int node = wave >> 2, t0 = (wave & 3) << 4;
  int l15 = lane & 15, q = lane >> 4;

  f4v affc[2], gatec[2], resc[2];
  #pragma unroll
  for (int i = 0; i < 2; i++) {
    affc[i] = (f4v){0.f,0.f,0.f,0.f};
    gatec[i] = (f4v){0.f,0.f,0.f,0.f};
    resc[i] = (f4v){0.f,0.f,0.f,0.f};
  }

  {   // res: A = h planes, K=32
    int ha = (node*64 + t0 + l15)*40 + q*8;
    s8v hhf = *(const s8v*)&Shh[ha];
    s8v hlf = *(const s8v*)&Shl[ha];
    #pragma unroll
    for (int ct = 0; ct < 2; ct++) {
      int wb = (ct*16 + l15)*32 + q*8;
      s8v wh = *(const s8v*)&wrh[wb];
      s8v wl = *(const s8v*)&wrl[wb];
      f4v d = resc[ct];
      d = __builtin_amdgcn_mfma_f32_16x16x32_bf16(hhf, wh, d, 0, 0, 0);
      d = __builtin_amdgcn_mfma_f32_16x16x32_bf16(hlf, wh, d, 0, 0, 0);
      d = __builtin_amdgcn_mfma_f32_16x16x32_bf16(hhf, wl, d, 0, 0, 0);
      resc[ct] = d;
    }
  }
  #pragma unroll
  for (int tap = 0; tap < 3; tap++) {   // causal conv = 3 shifted-row GEMMs
    int xa = (node*66 + t0 + l15 + tap)*40 + q*8;
    s8v xhf = *(const s8v*)&Sxh[xa];
    s8v xlf = *(const s8v*)&Sxl[xa];
    #pragma unroll
    for (int ct = 0; ct < 4; ct++) {    // 0,1 aff cols; 2,3 gate cols
      int wb = (tap*64 + ct*16 + l15)*32 + q*8;
      s8v wh = *(const s8v*)&wagh[wb];
      s8v wl = *(const s8v*)&wagl[wb];
      f4v d = (ct < 2) ? affc[ct] : gatec[ct-2];
      d = __builtin_amdgcn_mfma_f32_16x16x32_bf16(xhf, wh, d, 0, 0, 0);
      d = __builtin_amdgcn_mfma_f32_16x16x32_bf16(xlf, wh, d, 0, 0, 0);
      d = __builtin_amdgcn_mfma_f32_16x16x32_bf16(xhf, wl, d, 0, 0, 0);
      if (ct < 2) affc[ct] = d; else gatec[ct-2] = d;
    }
  }
  __syncthreads();   // all LDS A-reads done before z overlays the planes

  // ---- combine in C-fragment layout: col=o=l15(+16ct), row m=t0+q*4+r
  #pragma unroll
  for (int ct = 0; ct < 2; ct++) {
    int o = ct*16 + l15;
    float abias = ab[o] + rb[o];
    float gbias = gb[o];
    #pragma unroll
    for (int r = 0; r < 4; r++) {
      float a = affc[ct][r] + resc[ct][r] + abias;
      float g = gatec[ct][r] + gbias;
      float z = tanhf(a) * (1.f/(1.f + expf(-g)));
      Sz[node*2080 + o*65 + (t0 + q*4 + r)] = z;
    }
  }
  __syncthreads();

  // ---- mix: three 32x32 pointwise GEMMs on VALU (proven epilogue)
  int t = tid & 63;
  int og = wave;
  float y0a[2][4] = {}, y1a[2][4] = {}, y2a[2][4] = {};
  for (int c = 0; c < C_; c++) {
    float g0[4], g1[4], g2[4];
    #pragma unroll
    for (int jq = 0; jq < 4; jq++) {
      const float* gr = gcw + (og*4 + jq)*96;
      g0[jq] = gr[c]; g1[jq] = gr[32 + c]; g2[jq] = gr[64 + c];
    }
    #pragma unroll
    for (int nn = 0; nn < 2; nn++) {
      float zc = Sz[nn*2080 + c*65 + t];
      #pragma unroll
      for (int jq = 0; jq < 4; jq++) {
        y0a[nn][jq] = fmaf(g0[jq], zc, y0a[nn][jq]);
        y1a[nn][jq] = fmaf(g1[jq], zc, y1a[nn][jq]);
        y2a[nn][jq] = fmaf(g2[jq], zc, y2a[nn][jq]);
      }
    }
  }
  #pragma unroll
  for (int nn = 0; nn < 2; nn++)
    #pragma unroll
    for (int jq = 0; jq < 4; jq++) {
      int oo = og*4 + jq;
      size_t pp = off0 + (size_t)nn*T_ + (size_t)oo*CSTR + t;
      Y0[pp] = y0a[nn][jq] + gcb[oo];
      __hip_bfloat16 b1 = __float2bfloat16(y1a[nn][jq]);
      __hip_bfloat16 b2 = __float2bfloat16(y2a[nn][jq]);
      Y1h[pp] = *(u16*)&b1;
      Y2h[pp] = *(u16*)&b2;
    }
}

// ---------------------------------------------------------------------------
// Diffusion: A split-bf16 (hi+lo) x B single-plane bf16 -> 2 MFMA per tile.
// Proven two-barrier schedule; tile HALVED (64w x 128m, 2048 blocks) to raise
// co-resident block count (round-3 occupancy was 20.7% -> latency-bound;
// cross-block wave overlap is what hides the barrier drain in this schedule).
// acc 32 AGPR, LDS 20.5KB. Fused next-layer BN stats in the epilogue.
__global__ __launch_bounds__(256) void diff3_kernel(
    const u16* __restrict__ Y1h, const u16* __restrict__ Y2h,
    const short* __restrict__ ATh, const short* __restrict__ ATl,
    float* __restrict__ out, double* __restrict__ stp)
{
  __shared__ short Asd[2][64*40];    // AT tile [plane][w_local][k(32)+pad8]
  __shared__ short Bsd[128*40];      // Y  tile [m_local][k(32)+pad8], bf16 hi

  int tid = threadIdx.x;
  int bx = blockIdx.x;
  int mtile = bx & 15, wtile = bx >> 4;   // 16 mtiles x 8 wtiles
  int b = blockIdx.y;
  int w0 = wtile << 6;

  int lane = tid & 63;
  int wave = __builtin_amdgcn_readfirstlane(tid >> 6);
  int wi = wave & 1, wj = wave >> 1;
  int l15 = lane & 15, quad = lane >> 4;

  int offA[2], offB[4];
  #pragma unroll
  for (int ti = 0; ti < 2; ti++) offA[ti] = (wi*32 + ti*16 + l15)*40 + quad*8;
  #pragma unroll
  for (int tj = 0; tj < 4; tj++) offB[tj] = (wj*64 + tj*16 + l15)*40 + quad*8;

  f4v acc[8];
  #pragma unroll
  for (int i = 0; i < 8; i++) acc[i] = (f4v){0.f, 0.f, 0.f, 0.f};

  int t_l = tid & 63;
  int g = tid >> 6;

  for (int k0 = 0; k0 < 1024; k0 += 32) {
    __syncthreads();
    #pragma unroll
    for (int i = 0; i < 2; i++) {      // stage A hi/lo planes (64 rows)
      int idx = tid + i*256;
      int kq = idx & 3, wl = (idx >> 2) & 63, pl = idx >> 8;
      const short* sp = (pl ? ATl : ATh) + (size_t)(w0 + wl)*1024 + k0 + kq*8;
      int4 v = *(const int4*)sp;
      *(int4*)&Asd[pl][wl*40 + kq*8] = v;
    }
    {                                  // stage B (bf16 already; no cvt)
      int s  = k0 >> 9;
      int v0 = k0 & 511;
      const u16* Ys = (s ? Y2h : Y1h) + (size_t)b*BSTR;
      #pragma unroll
      for (int i = 0; i < 2; i++) {
        int sel = g*2 + i;
        int oo = sel & 1, kq = sel >> 1;
        int o = mtile*2 + oo;
        u16 hs[8];
        #pragma unroll
        for (int j = 0; j < 8; j++) {
          int v = v0 + kq*8 + j;
          hs[j] = (v < N_) ? Ys[((size_t)o*N_ + v)*T_ + t_l] : (u16)0;
        }
        *(int4*)&Bsd[(oo*64 + t_l)*40 + kq*8] = *(const int4*)hs;
      }
    }
    __syncthreads();
    s8v bh[4];
    #pragma unroll
    for (int tj = 0; tj < 4; tj++) bh[tj] = *(const s8v*)&Bsd[offB[tj]];
    #pragma unroll
    for (int ti = 0; ti < 2; ti++) {
      s8v ah = *(const s8v*)&Asd[0][offA[ti]];
      s8v al = *(const s8v*)&Asd[1][offA[ti]];
      #pragma unroll
      for (int tj = 0; tj < 4; tj++) {
        f4v d = acc[ti*4+tj];
        d = __builtin_amdgcn_mfma_f32_16x16x32_bf16(ah, bh[tj], d, 0, 0, 0);
        d = __builtin_amdgcn_mfma_f32_16x16x32_bf16(al, bh[tj], d, 0, 0, 0);
        acc[ti*4+tj] = d;
      }
    }
  }

  // epilogue: out += acc; capture final values for next layer's BN stats.
  int o = mtile*2 + wj;
  float s = 0.f, s2 = 0.f;
  #pragma unroll
  for (int tj = 0; tj < 4; tj++) {
    int t = tj*16 + l15;
    float* obase = out + (((size_t)b*C_ + o)*N_)*T_ + t;
    #pragma unroll
    for (int ti = 0; ti < 2; ti++) {
      int wbase = w0 + wi*32 + ti*16 + quad*4;
      #pragma unroll
      for (int r = 0; r < 4; r++) {
        int w = wbase + r;
        if (w < N_) {
          float* p = obase + (size_t)w*T_;
          float val = *p + acc[ti*4+tj][r];
          *p = val;
          s += val;
          s2 = fmaf(val, val, s2);
        }
      }
    }
  }
  if (stp) {
    #pragma unroll
    for (int d = 32; d > 0; d >>= 1) {
      s  += __shfl_down(s,  d, 64);
      s2 += __shfl_down(s2, d, 64);
    }
    if (lane == 0) {
      atomicAdd(&stp[2*o],     (double)s);
      atomicAdd(&stp[2*o + 1], (double)s2);
    }
  }
}

// ---------------------------------------------------------------------------
// Online-softmax attention, one node per wave, MLP fully in registers.
__global__ __launch_bounds__(256) void attn3_kernel(
    const float* __restrict__ hsrc, float* __restrict__ O,
    float* __restrict__ sden,
    const float* __restrict__ W1T, const float* __restrict__ b1,
    const float* __restrict__ W2, const float* __restrict__ b2,
    const float* __restrict__ w3, const float* __restrict__ b3,
    int init)
{
  int tid = threadIdx.x;
  int t = tid & 63;
  int g = __builtin_amdgcn_readfirstlane(tid >> 6);
  int bx = blockIdx.x;
  int b = bx / 125;
  int n = (bx - b*125)*4 + g;
  size_t off = (size_t)b*BSTR + (size_t)n*T_;

  float h1r[64];
  #pragma unroll
  for (int k = 0; k < 64; k++) h1r[k] = b1[k];
  for (int c = 0; c < C_; c++) {
    float xv = fmaxf(hsrc[off + (size_t)c*CSTR + t], 0.f);
    const float* wr = W1T + c*64;
    #pragma unroll
    for (int k = 0; k < 64; k++) h1r[k] = fmaf(wr[k], xv, h1r[k]);
  }
  #pragma unroll
  for (int k = 0; k < 64; k++) h1r[k] = fmaxf(h1r[k], 0.f);

  float e = b3[0];
  for (int j = 0; j < 64; j++) {
    const float* w2r = W2 + j*64;
    float a0 = 0.f, a1 = 0.f, a2 = 0.f, a3 = 0.f;
    #pragma unroll
    for (int i = 0; i < 64; i += 4) {
      a0 = fmaf(w2r[i+0], h1r[i+0], a0);
      a1 = fmaf(w2r[i+1], h1r[i+1], a1);
      a2 = fmaf(w2r[i+2], h1r[i+2], a2);
      a3 = fmaf(w2r[i+3], h1r[i+3], a3);
    }
    float a = b2[j] + ((a0+a1)+(a2+a3));
    e = fmaf(w3[j], fmaxf(a, 0.f), e);
  }
  float p = expf(e);      // e is O(1): no max-subtraction needed

  size_t si = (size_t)b*CSTR + (size_t)n*T_ + t;
  float so = init ? 0.f : sden[si];
  sden[si] = so + p;

  for (int c = 0; c < C_; c++) {
    size_t pi = off + (size_t)c*CSTR + t;
    float xv = fmaxf(hsrc[pi], 0.f);      // L1-hit re-read
    float ov = init ? 0.f : O[pi];
    O[pi] = fmaf(p, xv, ov);
  }
}

// ---------------------------------------------------------------------------
__global__ __launch_bounds__(256) void norm_kernel(float* __restrict__ O,
                                                   const float* __restrict__ sden) {
  unsigned idx = (blockIdx.x*256u + threadIdx.x) * 4u;
  unsigned b = idx / BSTR;
  unsigned r = idx - b*BSTR;
  unsigned nt = r % CSTR;
  float4 o = *(float4*)(O + idx);
  const float* sp = sden + (size_t)b*CSTR + nt;
  o.x /= sp[0]; o.y /= sp[1]; o.z /= sp[2]; o.w /= sp[3];
  *(float4*)(O + idx) = o;
}

// ---------------------------------------------------------------------------
extern "C" void kernel_launch(void* const* d_in, const int* in_sizes, int n_in,
                              void* d_out, int out_size, void* d_ws, size_t ws_size,
                              hipStream_t stream)
{
  const float* x    = (const float*)d_in[0];
  const float* sup  = (const float*)d_in[1];
  const float* bng  = (const float*)d_in[2];
  const float* bnb  = (const float*)d_in[3];
  const float* rw   = (const float*)d_in[4];
  const float* rb   = (const float*)d_in[5];
  const float* aw   = (const float*)d_in[6];
  const float* ab   = (const float*)d_in[7];
  const float* gw   = (const float*)d_in[8];
  const float* gb   = (const float*)d_in[9];
  const float* gcw  = (const float*)d_in[10];
  const float* gcb  = (const float*)d_in[11];
  const float* w1   = (const float*)d_in[12];
  const float* ab1  = (const float*)d_in[13];
  const float* w2   = (const float*)d_in[14];
  const float* ab2  = (const float*)d_in[15];
  const float* w3   = (const float*)d_in[16];
  const float* ab3  = (const float*)d_in[17];
  float* out = (float*)d_out;

  float* ws   = (float*)d_ws;
  float* bufA = ws;                       // Y0 / layer output h (float)
  u16*   Y1h  = (u16*)(ws + TENS);        // bf16 Y1 plane
  u16*   Y2h  = Y1h + TENS;               // bf16 Y2 plane
  float* sden = ws + (size_t)3*TENS;      // [B,N,T] softmax denom
  double* st  = (double*)(ws + (size_t)3*TENS + (size_t)B_*N_*T_);
  short* ATh  = (short*)(ws + (size_t)3*TENS + (size_t)B_*N_*T_ + 512);
  short* ATl  = ATh + (size_t)512*1024;
  float* W1T  = (float*)(ATl + (size_t)512*1024);
  u16* WAGh = (u16*)(W1T + 2048);         // [L][3][64][32]
  u16* WAGl = WAGh + 24576;
  u16* WRh  = WAGl + 24576;               // [L][32][32]
  u16* WRl  = WRh + 4096;

  zero_kernel<<<1, 256, 0, stream>>>(st);
  aconv_kernel<<<2048, 256, 0, stream>>>(sup, ATh, ATl);
  w1t_kernel<<<8, 256, 0, stream>>>(w1, W1T);
  wprep_kernel<<<112, 256, 0, stream>>>(aw, gw, rw, WAGh, WAGl, WRh, WRl);
  stats_kernel<<<dim3(C_, B_), 256, 0, stream>>>(x, st);
  // slot 0 of the stack = x
  attn3_kernel<<<B_*125, 256, 0, stream>>>(x, out, sden, W1T, ab1, w2, ab2, w3, ab3, 1);

  const float* hcur = x;
  for (int l = 0; l < L_; l++) {
    fuse4_kernel<<<B_*250, 512, 0, stream>>>(
        hcur, st + l*64, bng + l*C_, bnb + l*C_,
        WAGh + l*6144, WAGl + l*6144, WRh + l*1024, WRl + l*1024,
        rb + l*C_, ab + l*C_, gb + l*C_,
        gcw + l*C_*96, gcb + l*C_,
        bufA, Y1h, Y2h);
    diff3_kernel<<<dim3(128, B_), 256, 0, stream>>>(
        Y1h, Y2h, ATh, ATl, bufA, (l < L_-1) ? (st + (l+1)*64) : nullptr);
    attn3_kernel<<<B_*125, 256, 0, stream>>>(bufA, out, sden, W1T, ab1, w2, ab2, w3, ab3, 0);
    hcur = bufA;
  }
  norm_kernel<<<16000, 256, 0, stream>>>(out, sden);
}